// Round 7
// baseline (316.544 us; speedup 1.0000x reference)
//
#include <hip/hip_runtime.h>

#define F_IN 256
#define HC   128   // HEADS * C_OUT

typedef __attribute__((ext_vector_type(8))) short bf16x8;
typedef __attribute__((ext_vector_type(4))) float f32x4;
typedef __attribute__((ext_vector_type(2))) float f32x2;

// round-to-nearest-even fp32 -> bf16 (as ushort)
__device__ __forceinline__ unsigned short f2b(float f) {
    unsigned int u = __float_as_uint(f);
    return (unsigned short)((u + 0x7FFFu + ((u >> 16) & 1u)) >> 16);
}

// pack two fp32 -> bf16x2 (RNE), low = lo, high = hi
__device__ __forceinline__ unsigned int f2b_pk(float lo, float hi) {
    unsigned int ul = __float_as_uint(lo);
    unsigned int uh = __float_as_uint(hi);
    ul = ul + 0x7FFFu + ((ul >> 16) & 1u);
    uh = uh + 0x7FFFu + ((uh >> 16) & 1u);
    return __builtin_amdgcn_perm(uh, ul, 0x07060302);
}

#define DPP_ADD(x, ctrl) \
    x += __int_as_float(__builtin_amdgcn_update_dpp(0, __float_as_int(x), ctrl, 0xF, 0xF, true))

// sum across a 16-lane row for both components; broadcast to all 16 lanes
__device__ __forceinline__ f32x2 row_sum16_2(f32x2 v) {
    DPP_ADD(v.x, 0xB1);  DPP_ADD(v.y, 0xB1);   // quad_perm xor1
    DPP_ADD(v.x, 0x4E);  DPP_ADD(v.y, 0x4E);   // quad_perm xor2
    DPP_ADD(v.x, 0x141); DPP_ADD(v.y, 0x141);  // row_half_mirror (xor4)
    DPP_ADD(v.x, 0x140); DPP_ADD(v.y, 0x140);  // row_mirror (xor8)
    return v;
}

// ---------------- A: W pack only ----------------
// Pack W = [Ws | Wd] (256 x 256 combined) into B-fragment order with a COLUMN
// PERMUTATION chosen so the GEMM epilogue's per-lane outputs are contiguous:
//   fragment column slot (nt, m) serves packed output position
//       pos = (nt>>2)*64 + m*4 + (nt&3)
//   pos < 128 -> xsrc packed ushort pos (c = pos>>1, h = pos&1)
//   pos >=128 -> xdst packed ushort pos-128
__global__ __launch_bounds__(256) void k_prep(const float* __restrict__ Ws,
                                              const float* __restrict__ Wd,
                                              unsigned short* __restrict__ PB) {
    int tid = blockIdx.x * 256 + threadIdx.x;   // 8192 threads
    int nt  = tid >> 9;          // 0..15
    int rem = tid & 511;
    int t   = rem >> 6;          // 0..7
    int l   = rem & 63;
    int m   = l & 15;
    int w   = nt >> 2;
    int g   = nt & 3;
    int pos = w * 64 + m * 4 + g;            // 0..255
    int kbase = 32 * t + (l >> 4) * 8;

    const float* W;
    int n;
    if (pos < 128) {
        W = Ws; n = (pos & 1) * 64 + (pos >> 1);
    } else {
        int p2 = pos - 128;
        W = Wd; n = (p2 & 1) * 64 + (p2 >> 1);
    }
    union { bf16x8 v; unsigned short u[8]; } o;
#pragma unroll
    for (int j = 0; j < 8; ++j)
        o.u[j] = f2b(W[(kbase + j) * HC + n]);
    *(bf16x8*)(PB + (size_t)tid * 8) = o.v;
}

// ---------------- B: LDS-staged MFMA projection + dense edge-block build (fused) ----------------
// Blocks [0, LIST_BLOCKS): per-node dense index blocks, 4 spread sub-lists:
//   sub = i&3; slot = atomicAdd(&cnt4[d*4+sub],1);
//   slot<8 ? eidx[d*32 + sub*8 + slot] = s : overflow chain via head1/rec.
//   One 128B line holds all of a node's indices -> k_agg reads 1-2 lines, not ~10.
// Blocks [LIST_BLOCKS, ...): 64 rows x 256 cols per block, LDS-staged (swizzled)
//   -- byte-identical to the round-5 GEMM (measured 93-95 us fused).
#define LIST_BLOCKS 1024
__global__ __launch_bounds__(256) void k_gemm_list(const float* __restrict__ x,
                                                   const unsigned short* __restrict__ PB,
                                                   unsigned short* __restrict__ xsrc_pk,
                                                   unsigned short* __restrict__ xdst_pk, int N,
                                                   const int* __restrict__ src,
                                                   const int* __restrict__ dst, int E,
                                                   int* __restrict__ cnt4,
                                                   int* __restrict__ eidx,
                                                   int* __restrict__ head1,
                                                   uint2* __restrict__ rec) {
    if (blockIdx.x < LIST_BLOCKS) {
        int i = blockIdx.x * 256 + threadIdx.x;
        int stride = LIST_BLOCKS * 256;
        for (; i < E; i += stride) {
            int d = dst[i];
            int s = src[i];
            int sub = i & 3;
            int slot = atomicAdd(&cnt4[(size_t)d * 4 + sub], 1);
            if (slot < 8) {
                eidx[(size_t)d * 32 + sub * 8 + slot] = s;
            } else {
                int old = atomicExch(&head1[d], i);
                rec[i] = make_uint2((unsigned int)old, (unsigned int)s);
            }
        }
        return;
    }

    __shared__ unsigned short smem[64 * F_IN];   // 32 KB bf16 tile
    char* sb = (char*)smem;

    const int wave = threadIdx.x >> 6;
    const int lane = threadIdx.x & 63;
    const int m = lane & 15;
    const int q = lane >> 4;
    const long row0 = (long)(blockIdx.x - LIST_BLOCKS) * 64;

    // ---- stage 64x256 fp32 -> bf16 LDS (swizzled) ----
    {
        const int col = lane * 4;                 // float col
        const int wbyte_base = col * 2;           // byte-in-row before swizzle
#pragma unroll 8
        for (int i = 0; i < 16; ++i) {
            int row = i * 4 + wave;               // 0..63
            long grow = row0 + row;
            if (grow >= N) grow = N - 1;          // clamp (stores guarded later)
            float4 a = *(const float4*)(x + grow * F_IN + col);
            uint2 v;
            v.x = f2b_pk(a.x, a.y);
            v.y = f2b_pk(a.z, a.w);
            *(uint2*)(sb + row * 512 + (wbyte_base ^ ((row & 7) << 4))) = v;
        }
    }
    __syncthreads();

    f32x4 acc[4][4];   // [mt][g]
#pragma unroll
    for (int a = 0; a < 4; ++a)
#pragma unroll
        for (int b = 0; b < 4; ++b) acc[a][b] = (f32x4){0.f, 0.f, 0.f, 0.f};

#pragma unroll
    for (int t = 0; t < 8; ++t) {
        const int bytein = t * 64 + q * 16;       // byte offset within row
        bf16x8 af[4];
#pragma unroll
        for (int mt = 0; mt < 4; ++mt) {
            const int row = mt * 16 + m;
            af[mt] = *(const bf16x8*)(sb + row * 512 + (bytein ^ ((row & 7) << 4)));
        }
#pragma unroll
        for (int g = 0; g < 4; ++g) {
            const int nt = wave * 4 + g;
            bf16x8 bf = *(const bf16x8*)(PB + ((size_t)(nt * 8 + t) * 64 + lane) * 8);
#pragma unroll
            for (int mt = 0; mt < 4; ++mt)
                acc[mt][g] = __builtin_amdgcn_mfma_f32_16x16x32_bf16(af[mt], bf, acc[mt][g], 0, 0, 0);
        }
    }

    // D layout: col = m, row = q*4 + r. Column permutation in PB means this
    // lane's four g-values are packed positions wave*64 + m*4 + {0,1,2,3}
    // -> one 8B store per (mt, r).
    unsigned short* dstArr = (wave < 2) ? xsrc_pk : xdst_pk;
    const int colOff = ((wave & 1) * 64) + m * 4;
#pragma unroll
    for (int mt = 0; mt < 4; ++mt) {
#pragma unroll
        for (int r = 0; r < 4; ++r) {
            long row = row0 + mt * 16 + q * 4 + r;
            if (row >= N) continue;
            uint2 v;
            v.x = f2b_pk(acc[mt][0][r], acc[mt][1][r]);
            v.y = f2b_pk(acc[mt][2][r], acc[mt][3][r]);
            *(uint2*)(dstArr + row * HC + colOff) = v;
        }
    }
}

// ---------------- C: per-node softmax aggregation via dense index blocks ----------------
// one node per 16-lane group; lane s holds channels [4s,4s+4) of both heads as
// f32x2 (packed-f32 VALU). Indices come from the node's 128B eidx block
// (broadcast loads, L1/L2-resident) -> no random rec-line fetches. Rows
// prefetched 1 deep. Rare overflow (sub-list > 8) walks the legacy chain.
__global__ __launch_bounds__(256) void k_agg(const unsigned int* __restrict__ xsrc_u,
                                             const unsigned int* __restrict__ xdst_u,
                                             const int* __restrict__ cnt4,
                                             const int* __restrict__ eidx,
                                             const int* __restrict__ head1,
                                             const uint2* __restrict__ rec,
                                             const float* __restrict__ att,
                                             const float* __restrict__ bias,
                                             float* __restrict__ out, int N) {
    const int lane = threadIdx.x & 63;
    const int s = lane & 15;
    const int node = blockIdx.x * 16 + (threadIdx.x >> 4);   // 16 nodes per block
    const bool vn = node < N;
    const int nc = vn ? node : 0;

    // xd channels [4s,4s+4): each f32x2 = (head0, head1) of one channel
    uint4 D = *(const uint4*)(xdst_u + (size_t)nc * 64 + s * 4);
    f32x2 xd[4], at[4];
    {
        unsigned int du[4] = {D.x, D.y, D.z, D.w};
#pragma unroll
        for (int k = 0; k < 4; ++k)
            xd[k] = (f32x2){__uint_as_float(du[k] << 16),
                            __uint_as_float(du[k] & 0xFFFF0000u)};
    }
    {
        float4 A0 = *(const float4*)(att + s * 4);
        float4 A1 = *(const float4*)(att + 64 + s * 4);
        at[0] = (f32x2){A0.x, A1.x}; at[1] = (f32x2){A0.y, A1.y};
        at[2] = (f32x2){A0.z, A1.z}; at[3] = (f32x2){A0.w, A1.w};
    }

    f32x2 l2 = (f32x2){0.f, 0.f};
    f32x2 o2[4];
#pragma unroll
    for (int k = 0; k < 4; ++k) o2[k] = (f32x2){0.f, 0.f};

    // dense per-node index block: 4 sub-lists of up to 8
    uint4 c4 = *(const uint4*)(cnt4 + (size_t)nc * 4);
    int d0 = min((int)c4.x, 8), d1 = min((int)c4.y, 8);
    int d2 = min((int)c4.z, 8), d3 = min((int)c4.w, 8);
    const int p1 = d0, p2 = d0 + d1, p3 = d0 + d1 + d2;
    const int T  = vn ? (p3 + d3) : 0;
    const int* nb = eidx + (size_t)nc * 32;

    // t -> flat position in the node's 128B block
    auto nbidx = [&](int t) -> int {
        int pos = (t < p1) ? t
                : (t < p2) ? (8  + t - p1)
                : (t < p3) ? (16 + t - p2)
                :            (24 + t - p3);
        return nb[pos];
    };

    int t = 0;
    bool act = t < T;
    int j = act ? nbidx(0) : 0;
    uint4 U = *(const uint4*)(xsrc_u + (size_t)j * 64 + s * 4);

    while (__any(act)) {
        if (act) {
            bool actn = (t + 1) < T;
            int jn = actn ? nbidx(t + 1) : 0;
            uint4 Un = *(const uint4*)(xsrc_u + (size_t)jn * 64 + s * 4);  // prefetch

            unsigned int cu[4] = {U.x, U.y, U.z, U.w};
            f32x2 xj[4];
            f32x2 s2 = (f32x2){0.f, 0.f};
#pragma unroll
            for (int k = 0; k < 4; ++k) {
                xj[k] = (f32x2){__uint_as_float(cu[k] << 16),
                                __uint_as_float(cu[k] & 0xFFFF0000u)};
                f32x2 e2 = xj[k] + xd[k];
                f32x2 e5 = e2 * 0.2f;
                f32x2 le;
                le.x = fmaxf(e2.x, e5.x);
                le.y = fmaxf(e2.y, e5.y);
                s2 += at[k] * le;
            }

            s2 = row_sum16_2(s2);
            f32x2 w2;
            w2.x = __expf(s2.x);
            w2.y = __expf(s2.y);
            l2 += w2;
#pragma unroll
            for (int k = 0; k < 4; ++k) o2[k] += w2 * xj[k];

            t = t + 1; act = actn; U = Un;
        }
    }

    // ---- rare overflow chain (any sub-list deeper than 8) ----
    int e = vn ? head1[nc] : -1;
    if (__any(e >= 0)) {
        uint2 r = rec[e >= 0 ? e : 0];
        while (__any(e >= 0)) {
            if (e >= 0) {
                int jo = (int)r.y;
                uint4 Uo = *(const uint4*)(xsrc_u + (size_t)jo * 64 + s * 4);
                int en = (int)r.x;
                if (en >= 0) r = rec[en];
                unsigned int cu[4] = {Uo.x, Uo.y, Uo.z, Uo.w};
                f32x2 xj[4];
                f32x2 s2 = (f32x2){0.f, 0.f};
#pragma unroll
                for (int k = 0; k < 4; ++k) {
                    xj[k] = (f32x2){__uint_as_float(cu[k] << 16),
                                    __uint_as_float(cu[k] & 0xFFFF0000u)};
                    f32x2 e2 = xj[k] + xd[k];
                    f32x2 e5 = e2 * 0.2f;
                    f32x2 le;
                    le.x = fmaxf(e2.x, e5.x);
                    le.y = fmaxf(e2.y, e5.y);
                    s2 += at[k] * le;
                }
                s2 = row_sum16_2(s2);
                f32x2 w2;
                w2.x = __expf(s2.x);
                w2.y = __expf(s2.y);
                l2 += w2;
#pragma unroll
                for (int k = 0; k < 4; ++k) o2[k] += w2 * xj[k];
                e = en;
            }
        }
    }

    if (vn) {
        float inv0 = __builtin_amdgcn_rcpf(l2.x + 1e-16f);
        float inv1 = __builtin_amdgcn_rcpf(l2.y + 1e-16f);
        float4 B0 = *(const float4*)(bias + s * 4);
        float4 B1 = *(const float4*)(bias + 64 + s * 4);
        float4 R0 = {o2[0].x * inv0 + B0.x, o2[1].x * inv0 + B0.y,
                     o2[2].x * inv0 + B0.z, o2[3].x * inv0 + B0.w};
        float4 R1 = {o2[0].y * inv1 + B1.x, o2[1].y * inv1 + B1.y,
                     o2[2].y * inv1 + B1.z, o2[3].y * inv1 + B1.w};
        *(float4*)(out + (size_t)node * HC + s * 4) = R0;
        *(float4*)(out + (size_t)node * HC + 64 + s * 4) = R1;
    }
}

extern "C" void kernel_launch(void* const* d_in, const int* in_sizes, int n_in,
                              void* d_out, int out_size, void* d_ws, size_t ws_size,
                              hipStream_t stream) {
    const float* x    = (const float*)d_in[0];
    const int*   ei   = (const int*)d_in[1];
    const float* Ws   = (const float*)d_in[2];
    const float* Wd   = (const float*)d_in[3];
    const float* att  = (const float*)d_in[4];
    const float* bias = (const float*)d_in[5];
    float* out = (float*)d_out;

    const int N = in_sizes[0] / F_IN;
    const int E = in_sizes[1] / 2;
    const int* src = ei;
    const int* dst = ei + E;

    char* ws = (char*)d_ws;
    size_t off = 0;
    auto alloc = [&](size_t bytes) -> char* {
        off = (off + 255) & ~(size_t)255;
        char* p = ws + off;
        off += bytes;
        return p;
    };
    unsigned short* xsrc_pk = (unsigned short*)alloc((size_t)N * HC * sizeof(unsigned short)); // 25.6 MB
    unsigned short* xdst_pk = (unsigned short*)alloc((size_t)N * HC * sizeof(unsigned short)); // 25.6 MB
    unsigned short* PB = (unsigned short*)alloc(256 * 256 * sizeof(unsigned short));           // 128 KB
    int*   cnt4  = (int*)alloc((size_t)N * 4 * sizeof(int));                                   // 1.6 MB
    int*   head1 = (int*)alloc((size_t)N * sizeof(int));                                       // 400 KB
    int*   eidx  = (int*)alloc((size_t)N * 32 * sizeof(int));                                  // 12.8 MB
    uint2* rec   = (uint2*)alloc((size_t)E * sizeof(uint2));                                   // 8 MB

    hipMemsetAsync(cnt4, 0, (size_t)N * 4 * sizeof(int), stream);
    hipMemsetAsync(head1, 0xFF, (size_t)N * sizeof(int), stream);   // -1 sentinels

    k_prep<<<32, 256, 0, stream>>>(Ws, Wd, PB);
    k_gemm_list<<<LIST_BLOCKS + (int)((N + 63) / 64), 256, 0, stream>>>(
        x, PB, xsrc_pk, xdst_pk, N, src, dst, E, cnt4, eidx, head1, rec);
    k_agg<<<(N + 15) / 16, 256, 0, stream>>>((const unsigned int*)xsrc_pk,
                                             (const unsigned int*)xdst_pk,
                                             cnt4, eidx, head1, rec, att, bias, out, N);
}

// Round 8
// 291.380 us; speedup vs baseline: 1.0864x; 1.0864x over previous
//
#include <hip/hip_runtime.h>

#define F_IN 256
#define HC   128   // HEADS * C_OUT

typedef __attribute__((ext_vector_type(8))) short bf16x8;
typedef __attribute__((ext_vector_type(4))) float f32x4;
typedef __attribute__((ext_vector_type(2))) float f32x2;

// round-to-nearest-even fp32 -> bf16 (as ushort)
__device__ __forceinline__ unsigned short f2b(float f) {
    unsigned int u = __float_as_uint(f);
    return (unsigned short)((u + 0x7FFFu + ((u >> 16) & 1u)) >> 16);
}

// pack two fp32 -> bf16x2 (RNE), low = lo, high = hi
__device__ __forceinline__ unsigned int f2b_pk(float lo, float hi) {
    unsigned int ul = __float_as_uint(lo);
    unsigned int uh = __float_as_uint(hi);
    ul = ul + 0x7FFFu + ((ul >> 16) & 1u);
    uh = uh + 0x7FFFu + ((uh >> 16) & 1u);
    return __builtin_amdgcn_perm(uh, ul, 0x07060302);
}

#define DPP_ADD(x, ctrl) \
    x += __int_as_float(__builtin_amdgcn_update_dpp(0, __float_as_int(x), ctrl, 0xF, 0xF, true))

// sum across a 16-lane row for both components; broadcast to all 16 lanes
__device__ __forceinline__ f32x2 row_sum16_2(f32x2 v) {
    DPP_ADD(v.x, 0xB1);  DPP_ADD(v.y, 0xB1);   // quad_perm xor1
    DPP_ADD(v.x, 0x4E);  DPP_ADD(v.y, 0x4E);   // quad_perm xor2
    DPP_ADD(v.x, 0x141); DPP_ADD(v.y, 0x141);  // row_half_mirror (xor4)
    DPP_ADD(v.x, 0x140); DPP_ADD(v.y, 0x140);  // row_mirror (xor8)
    return v;
}

// ---------------- A: W pack only ----------------
// Pack W = [Ws | Wd] (256 x 256 combined) into B-fragment order with a COLUMN
// PERMUTATION chosen so the GEMM epilogue's per-lane outputs are contiguous:
//   fragment column slot (nt, m) serves packed output position
//       pos = (nt>>2)*64 + m*4 + (nt&3)
//   pos < 128 -> xsrc packed ushort pos (c = pos>>1, h = pos&1)
//   pos >=128 -> xdst packed ushort pos-128
__global__ __launch_bounds__(256) void k_prep(const float* __restrict__ Ws,
                                              const float* __restrict__ Wd,
                                              unsigned short* __restrict__ PB) {
    int tid = blockIdx.x * 256 + threadIdx.x;   // 8192 threads
    int nt  = tid >> 9;          // 0..15
    int rem = tid & 511;
    int t   = rem >> 6;          // 0..7
    int l   = rem & 63;
    int m   = l & 15;
    int w   = nt >> 2;
    int g   = nt & 3;
    int pos = w * 64 + m * 4 + g;            // 0..255
    int kbase = 32 * t + (l >> 4) * 8;

    const float* W;
    int n;
    if (pos < 128) {
        W = Ws; n = (pos & 1) * 64 + (pos >> 1);
    } else {
        int p2 = pos - 128;
        W = Wd; n = (p2 & 1) * 64 + (p2 >> 1);
    }
    union { bf16x8 v; unsigned short u[8]; } o;
#pragma unroll
    for (int j = 0; j < 8; ++j)
        o.u[j] = f2b(W[(kbase + j) * HC + n]);
    *(bf16x8*)(PB + (size_t)tid * 8) = o.v;
}

// ---------------- B: LDS-staged MFMA projection + single-chain list build (fused) ----------------
// Blocks [0, LIST_BLOCKS): one chain per node, 4-wide BATCHED:
//   load 4 (dst,src) pairs, issue 4 independent atomicExch (concurrent round
//   trips), then 4 coalesced rec stores. Removes the per-thread serial chain
//   of ~4 dependent ~700cy atomic round trips.
// Blocks [LIST_BLOCKS, ...): 64 rows x 256 cols per block, LDS-staged
//   (swizzled) -- byte-identical to round 5's GEMM phase.
#define LIST_BLOCKS 1024
__global__ __launch_bounds__(256) void k_gemm_list(const float* __restrict__ x,
                                                   const unsigned short* __restrict__ PB,
                                                   unsigned short* __restrict__ xsrc_pk,
                                                   unsigned short* __restrict__ xdst_pk, int N,
                                                   const int* __restrict__ src,
                                                   const int* __restrict__ dst, int E,
                                                   int* __restrict__ head1,
                                                   uint2* __restrict__ rec) {
    if (blockIdx.x < LIST_BLOCKS) {
        const int S = LIST_BLOCKS * 256;
        for (int i0 = blockIdx.x * 256 + threadIdx.x; i0 < E; i0 += 4 * S) {
            int d[4], s[4];
            bool v[4];
#pragma unroll
            for (int k = 0; k < 4; ++k) {
                int i = i0 + k * S;
                v[k] = i < E;
                int ic = v[k] ? i : 0;
                d[k] = dst[ic];
                s[k] = src[ic];
            }
            int old[4];
#pragma unroll
            for (int k = 0; k < 4; ++k)
                if (v[k]) old[k] = atomicExch(&head1[d[k]], i0 + k * S);
#pragma unroll
            for (int k = 0; k < 4; ++k)
                if (v[k]) rec[i0 + k * S] =
                    make_uint2((unsigned int)old[k], (unsigned int)s[k]);
        }
        return;
    }

    __shared__ unsigned short smem[64 * F_IN];   // 32 KB bf16 tile
    char* sb = (char*)smem;

    const int wave = threadIdx.x >> 6;
    const int lane = threadIdx.x & 63;
    const int m = lane & 15;
    const int q = lane >> 4;
    const long row0 = (long)(blockIdx.x - LIST_BLOCKS) * 64;

    // ---- stage 64x256 fp32 -> bf16 LDS (swizzled) ----
    {
        const int col = lane * 4;                 // float col
        const int wbyte_base = col * 2;           // byte-in-row before swizzle
#pragma unroll 8
        for (int i = 0; i < 16; ++i) {
            int row = i * 4 + wave;               // 0..63
            long grow = row0 + row;
            if (grow >= N) grow = N - 1;          // clamp (stores guarded later)
            float4 a = *(const float4*)(x + grow * F_IN + col);
            uint2 v;
            v.x = f2b_pk(a.x, a.y);
            v.y = f2b_pk(a.z, a.w);
            *(uint2*)(sb + row * 512 + (wbyte_base ^ ((row & 7) << 4))) = v;
        }
    }
    __syncthreads();

    f32x4 acc[4][4];   // [mt][g]
#pragma unroll
    for (int a = 0; a < 4; ++a)
#pragma unroll
        for (int b = 0; b < 4; ++b) acc[a][b] = (f32x4){0.f, 0.f, 0.f, 0.f};

#pragma unroll
    for (int t = 0; t < 8; ++t) {
        const int bytein = t * 64 + q * 16;       // byte offset within row
        bf16x8 af[4];
#pragma unroll
        for (int mt = 0; mt < 4; ++mt) {
            const int row = mt * 16 + m;
            af[mt] = *(const bf16x8*)(sb + row * 512 + (bytein ^ ((row & 7) << 4)));
        }
#pragma unroll
        for (int g = 0; g < 4; ++g) {
            const int nt = wave * 4 + g;
            bf16x8 bf = *(const bf16x8*)(PB + ((size_t)(nt * 8 + t) * 64 + lane) * 8);
#pragma unroll
            for (int mt = 0; mt < 4; ++mt)
                acc[mt][g] = __builtin_amdgcn_mfma_f32_16x16x32_bf16(af[mt], bf, acc[mt][g], 0, 0, 0);
        }
    }

    // D layout: col = m, row = q*4 + r. Column permutation in PB means this
    // lane's four g-values are packed positions wave*64 + m*4 + {0,1,2,3}
    // -> one 8B store per (mt, r).
    unsigned short* dstArr = (wave < 2) ? xsrc_pk : xdst_pk;
    const int colOff = ((wave & 1) * 64) + m * 4;
#pragma unroll
    for (int mt = 0; mt < 4; ++mt) {
#pragma unroll
        for (int r = 0; r < 4; ++r) {
            long row = row0 + mt * 16 + q * 4 + r;
            if (row >= N) continue;
            uint2 v;
            v.x = f2b_pk(acc[mt][0][r], acc[mt][1][r]);
            v.y = f2b_pk(acc[mt][2][r], acc[mt][3][r]);
            *(uint2*)(dstArr + row * HC + colOff) = v;
        }
    }
}

// ---------------- C: per-node softmax aggregation, one node per 16-lane group ----------------
// lane = 16*g + s: group g owns node blockIdx.x*16 + wid*4 + g (single chain walk).
// lane s holds channels [4s,4s+4); each packed dword = one channel, (h0,h1) ->
// heads map onto f32x2 so channel math emits packed-f32 VALU ops.
// leaky(e) = max(e, 0.2e) exactly. rec prefetched 1 hop ahead; next xsrc row
// prefetched before the rowsum/exp/accum tail. No cross-group combine needed.
__global__ __launch_bounds__(256) void k_agg(const unsigned int* __restrict__ xsrc_u,
                                             const unsigned int* __restrict__ xdst_u,
                                             const int* __restrict__ head1,
                                             const uint2* __restrict__ rec,
                                             const float* __restrict__ att,
                                             const float* __restrict__ bias,
                                             float* __restrict__ out, int N) {
    const int lane = threadIdx.x & 63;
    const int s = lane & 15;
    const int node = blockIdx.x * 16 + (threadIdx.x >> 4);   // 16 nodes per block
    const bool vn = node < N;
    const int nc = vn ? node : 0;

    // xd channels [4s,4s+4): each f32x2 = (head0, head1) of one channel
    uint4 D = *(const uint4*)(xdst_u + (size_t)nc * 64 + s * 4);
    f32x2 xd[4], at[4];
    {
        unsigned int du[4] = {D.x, D.y, D.z, D.w};
#pragma unroll
        for (int k = 0; k < 4; ++k)
            xd[k] = (f32x2){__uint_as_float(du[k] << 16),
                            __uint_as_float(du[k] & 0xFFFF0000u)};
    }
    {
        float4 A0 = *(const float4*)(att + s * 4);
        float4 A1 = *(const float4*)(att + 64 + s * 4);
        at[0] = (f32x2){A0.x, A1.x}; at[1] = (f32x2){A0.y, A1.y};
        at[2] = (f32x2){A0.z, A1.z}; at[3] = (f32x2){A0.w, A1.w};
    }

    f32x2 l2 = (f32x2){0.f, 0.f};
    f32x2 o2[4];
#pragma unroll
    for (int k = 0; k < 4; ++k) o2[k] = (f32x2){0.f, 0.f};

    int e = vn ? head1[nc] : -1;
    uint2 r = rec[e >= 0 ? e : 0];
    int j = (e >= 0) ? (int)r.y : 0;
    uint4 U = *(const uint4*)(xsrc_u + (size_t)j * 64 + s * 4);

    while (__any(e >= 0)) {
        if (e >= 0) {
            int en = (int)r.x;
            uint2 rn = rec[en >= 0 ? en : 0];          // next-hop record prefetch

            unsigned int cu[4] = {U.x, U.y, U.z, U.w};
            f32x2 xj[4];
            f32x2 s2 = (f32x2){0.f, 0.f};
#pragma unroll
            for (int k = 0; k < 4; ++k) {
                xj[k] = (f32x2){__uint_as_float(cu[k] << 16),
                                __uint_as_float(cu[k] & 0xFFFF0000u)};
                f32x2 e2 = xj[k] + xd[k];
                f32x2 e5 = e2 * 0.2f;
                f32x2 le;
                le.x = fmaxf(e2.x, e5.x);
                le.y = fmaxf(e2.y, e5.y);
                s2 += at[k] * le;
            }

            // prefetch next row while reduction + exp + accum run
            int jn = (en >= 0) ? (int)rn.y : 0;
            uint4 Un = *(const uint4*)(xsrc_u + (size_t)jn * 64 + s * 4);

            s2 = row_sum16_2(s2);
            f32x2 w2;
            w2.x = __expf(s2.x);
            w2.y = __expf(s2.y);
            l2 += w2;
#pragma unroll
            for (int k = 0; k < 4; ++k) o2[k] += w2 * xj[k];

            e = en; r = rn; U = Un;
        }
    }

    if (vn) {
        float inv0 = __builtin_amdgcn_rcpf(l2.x + 1e-16f);
        float inv1 = __builtin_amdgcn_rcpf(l2.y + 1e-16f);
        float4 B0 = *(const float4*)(bias + s * 4);
        float4 B1 = *(const float4*)(bias + 64 + s * 4);
        float4 R0 = {o2[0].x * inv0 + B0.x, o2[1].x * inv0 + B0.y,
                     o2[2].x * inv0 + B0.z, o2[3].x * inv0 + B0.w};
        float4 R1 = {o2[0].y * inv1 + B1.x, o2[1].y * inv1 + B1.y,
                     o2[2].y * inv1 + B1.z, o2[3].y * inv1 + B1.w};
        *(float4*)(out + (size_t)node * HC + s * 4) = R0;
        *(float4*)(out + (size_t)node * HC + 64 + s * 4) = R1;
    }
}

extern "C" void kernel_launch(void* const* d_in, const int* in_sizes, int n_in,
                              void* d_out, int out_size, void* d_ws, size_t ws_size,
                              hipStream_t stream) {
    const float* x    = (const float*)d_in[0];
    const int*   ei   = (const int*)d_in[1];
    const float* Ws   = (const float*)d_in[2];
    const float* Wd   = (const float*)d_in[3];
    const float* att  = (const float*)d_in[4];
    const float* bias = (const float*)d_in[5];
    float* out = (float*)d_out;

    const int N = in_sizes[0] / F_IN;
    const int E = in_sizes[1] / 2;
    const int* src = ei;
    const int* dst = ei + E;

    char* ws = (char*)d_ws;
    size_t off = 0;
    auto alloc = [&](size_t bytes) -> char* {
        off = (off + 255) & ~(size_t)255;
        char* p = ws + off;
        off += bytes;
        return p;
    };
    unsigned short* xsrc_pk = (unsigned short*)alloc((size_t)N * HC * sizeof(unsigned short)); // 25.6 MB
    unsigned short* xdst_pk = (unsigned short*)alloc((size_t)N * HC * sizeof(unsigned short)); // 25.6 MB
    unsigned short* PB = (unsigned short*)alloc(256 * 256 * sizeof(unsigned short));           // 128 KB
    int*   head1 = (int*)alloc((size_t)N * sizeof(int));                                       // 400 KB
    uint2* rec   = (uint2*)alloc((size_t)E * sizeof(uint2));                                   // 8 MB

    hipMemsetAsync(head1, 0xFF, (size_t)N * sizeof(int), stream);   // -1 sentinels

    k_prep<<<32, 256, 0, stream>>>(Ws, Wd, PB);
    k_gemm_list<<<LIST_BLOCKS + (int)((N + 63) / 64), 256, 0, stream>>>(
        x, PB, xsrc_pk, xdst_pk, N, src, dst, E, head1, rec);
    k_agg<<<(N + 15) / 16, 256, 0, stream>>>((const unsigned int*)xsrc_pk,
                                             (const unsigned int*)xdst_pk,
                                             head1, rec, att, bias, out, N);
}

// Round 9
// 283.674 us; speedup vs baseline: 1.1159x; 1.0272x over previous
//
#include <hip/hip_runtime.h>

#define F_IN 256
#define HC   128   // HEADS * C_OUT

typedef __attribute__((ext_vector_type(8))) short bf16x8;
typedef __attribute__((ext_vector_type(4))) float f32x4;
typedef __attribute__((ext_vector_type(2))) float f32x2;

// round-to-nearest-even fp32 -> bf16 (as ushort)
__device__ __forceinline__ unsigned short f2b(float f) {
    unsigned int u = __float_as_uint(f);
    return (unsigned short)((u + 0x7FFFu + ((u >> 16) & 1u)) >> 16);
}

// pack two fp32 -> bf16x2 (RNE), low = lo, high = hi
__device__ __forceinline__ unsigned int f2b_pk(float lo, float hi) {
    unsigned int ul = __float_as_uint(lo);
    unsigned int uh = __float_as_uint(hi);
    ul = ul + 0x7FFFu + ((ul >> 16) & 1u);
    uh = uh + 0x7FFFu + ((uh >> 16) & 1u);
    return __builtin_amdgcn_perm(uh, ul, 0x07060302);
}

#define DPP_ADD(x, ctrl) \
    x += __int_as_float(__builtin_amdgcn_update_dpp(0, __float_as_int(x), ctrl, 0xF, 0xF, true))

// sum across a 16-lane row for both components; broadcast to all 16 lanes
__device__ __forceinline__ f32x2 row_sum16_2(f32x2 v) {
    DPP_ADD(v.x, 0xB1);  DPP_ADD(v.y, 0xB1);   // quad_perm xor1
    DPP_ADD(v.x, 0x4E);  DPP_ADD(v.y, 0x4E);   // quad_perm xor2
    DPP_ADD(v.x, 0x141); DPP_ADD(v.y, 0x141);  // row_half_mirror (xor4)
    DPP_ADD(v.x, 0x140); DPP_ADD(v.y, 0x140);  // row_mirror (xor8)
    return v;
}

// ---------------- A: W pack + head1 init (fused; removes a memset dispatch) ----------------
// Blocks [0,32): pack W = [Ws | Wd] (256 x 256 combined) into B-fragment order
// with a COLUMN PERMUTATION chosen so the GEMM epilogue's per-lane outputs are
// contiguous:
//   fragment column slot (nt, m) serves packed output position
//       pos = (nt>>2)*64 + m*4 + (nt&3)
//   pos < 128 -> xsrc packed ushort pos (c = pos>>1, h = pos&1)
//   pos >=128 -> xdst packed ushort pos-128
// Blocks [32, 32+160): head1[i] = -1 grid-stride.
__global__ __launch_bounds__(256) void k_prep(const float* __restrict__ Ws,
                                              const float* __restrict__ Wd,
                                              unsigned short* __restrict__ PB,
                                              int* __restrict__ head1, int N) {
    if (blockIdx.x >= 32) {
        int i = (blockIdx.x - 32) * 256 + threadIdx.x;
        int stride = 160 * 256;
        for (; i < N; i += stride) head1[i] = -1;
        return;
    }
    int tid = blockIdx.x * 256 + threadIdx.x;   // 8192 threads
    int nt  = tid >> 9;          // 0..15
    int rem = tid & 511;
    int t   = rem >> 6;          // 0..7
    int l   = rem & 63;
    int m   = l & 15;
    int w   = nt >> 2;
    int g   = nt & 3;
    int pos = w * 64 + m * 4 + g;            // 0..255
    int kbase = 32 * t + (l >> 4) * 8;

    const float* W;
    int n;
    if (pos < 128) {
        W = Ws; n = (pos & 1) * 64 + (pos >> 1);
    } else {
        int p2 = pos - 128;
        W = Wd; n = (p2 & 1) * 64 + (p2 >> 1);
    }
    union { bf16x8 v; unsigned short u[8]; } o;
#pragma unroll
    for (int j = 0; j < 8; ++j)
        o.u[j] = f2b(W[(kbase + j) * HC + n]);
    *(bf16x8*)(PB + (size_t)tid * 8) = o.v;
}

// ---------------- B: LDS-staged MFMA projection + single-chain list build (fused) ----------------
// Blocks [0, LIST_BLOCKS): one chain per node:
//   old = atomicExch(&head1[dst], e); rec[e] = {next=old, src}
// Blocks [LIST_BLOCKS, ...): 64 rows x 256 cols per block, LDS-staged (swizzled).
// (Measured best configuration: round 5, 93-95 us fused.)
#define LIST_BLOCKS 1024
__global__ __launch_bounds__(256) void k_gemm_list(const float* __restrict__ x,
                                                   const unsigned short* __restrict__ PB,
                                                   unsigned short* __restrict__ xsrc_pk,
                                                   unsigned short* __restrict__ xdst_pk, int N,
                                                   const int* __restrict__ src,
                                                   const int* __restrict__ dst, int E,
                                                   int* __restrict__ head1,
                                                   uint2* __restrict__ rec) {
    if (blockIdx.x < LIST_BLOCKS) {
        int i = blockIdx.x * 256 + threadIdx.x;
        int stride = LIST_BLOCKS * 256;
        for (; i < E; i += stride) {
            int d = dst[i];
            int s = src[i];
            int old = atomicExch(&head1[d], i);
            rec[i] = make_uint2((unsigned int)old, (unsigned int)s);
        }
        return;
    }

    __shared__ unsigned short smem[64 * F_IN];   // 32 KB bf16 tile
    char* sb = (char*)smem;

    const int wave = threadIdx.x >> 6;
    const int lane = threadIdx.x & 63;
    const int m = lane & 15;
    const int q = lane >> 4;
    const long row0 = (long)(blockIdx.x - LIST_BLOCKS) * 64;

    // ---- stage 64x256 fp32 -> bf16 LDS (swizzled) ----
    {
        const int col = lane * 4;                 // float col
        const int wbyte_base = col * 2;           // byte-in-row before swizzle
#pragma unroll 8
        for (int i = 0; i < 16; ++i) {
            int row = i * 4 + wave;               // 0..63
            long grow = row0 + row;
            if (grow >= N) grow = N - 1;          // clamp (stores guarded later)
            float4 a = *(const float4*)(x + grow * F_IN + col);
            uint2 v;
            v.x = f2b_pk(a.x, a.y);
            v.y = f2b_pk(a.z, a.w);
            *(uint2*)(sb + row * 512 + (wbyte_base ^ ((row & 7) << 4))) = v;
        }
    }
    __syncthreads();

    f32x4 acc[4][4];   // [mt][g]
#pragma unroll
    for (int a = 0; a < 4; ++a)
#pragma unroll
        for (int b = 0; b < 4; ++b) acc[a][b] = (f32x4){0.f, 0.f, 0.f, 0.f};

#pragma unroll
    for (int t = 0; t < 8; ++t) {
        const int bytein = t * 64 + q * 16;       // byte offset within row
        bf16x8 af[4];
#pragma unroll
        for (int mt = 0; mt < 4; ++mt) {
            const int row = mt * 16 + m;
            af[mt] = *(const bf16x8*)(sb + row * 512 + (bytein ^ ((row & 7) << 4)));
        }
#pragma unroll
        for (int g = 0; g < 4; ++g) {
            const int nt = wave * 4 + g;
            bf16x8 bf = *(const bf16x8*)(PB + ((size_t)(nt * 8 + t) * 64 + lane) * 8);
#pragma unroll
            for (int mt = 0; mt < 4; ++mt)
                acc[mt][g] = __builtin_amdgcn_mfma_f32_16x16x32_bf16(af[mt], bf, acc[mt][g], 0, 0, 0);
        }
    }

    // D layout: col = m, row = q*4 + r. Column permutation in PB means this
    // lane's four g-values are packed positions wave*64 + m*4 + {0,1,2,3}
    // -> one 8B store per (mt, r).
    unsigned short* dstArr = (wave < 2) ? xsrc_pk : xdst_pk;
    const int colOff = ((wave & 1) * 64) + m * 4;
#pragma unroll
    for (int mt = 0; mt < 4; ++mt) {
#pragma unroll
        for (int r = 0; r < 4; ++r) {
            long row = row0 + mt * 16 + q * 4 + r;
            if (row >= N) continue;
            uint2 v;
            v.x = f2b_pk(acc[mt][0][r], acc[mt][1][r]);
            v.y = f2b_pk(acc[mt][2][r], acc[mt][3][r]);
            *(uint2*)(dstArr + row * HC + colOff) = v;
        }
    }
}

// ---------------- C: per-node softmax aggregation, one node per 16-lane group ----------------
// lane = 16*g + s: group g owns node blockIdx.x*16 + wid*4 + g (single chain walk).
// lane s holds channels [4s,4s+4); each packed dword = one channel, (h0,h1) ->
// heads map onto f32x2 so channel math emits packed-f32 VALU ops.
// leaky(e) = max(e, 0.2e) exactly. rec prefetched 1 hop ahead; next xsrc row
// prefetched before the rowsum/exp/accum tail. No cross-group combine needed.
__global__ __launch_bounds__(256) void k_agg(const unsigned int* __restrict__ xsrc_u,
                                             const unsigned int* __restrict__ xdst_u,
                                             const int* __restrict__ head1,
                                             const uint2* __restrict__ rec,
                                             const float* __restrict__ att,
                                             const float* __restrict__ bias,
                                             float* __restrict__ out, int N) {
    const int lane = threadIdx.x & 63;
    const int s = lane & 15;
    const int node = blockIdx.x * 16 + (threadIdx.x >> 4);   // 16 nodes per block
    const bool vn = node < N;
    const int nc = vn ? node : 0;

    // xd channels [4s,4s+4): each f32x2 = (head0, head1) of one channel
    uint4 D = *(const uint4*)(xdst_u + (size_t)nc * 64 + s * 4);
    f32x2 xd[4], at[4];
    {
        unsigned int du[4] = {D.x, D.y, D.z, D.w};
#pragma unroll
        for (int k = 0; k < 4; ++k)
            xd[k] = (f32x2){__uint_as_float(du[k] << 16),
                            __uint_as_float(du[k] & 0xFFFF0000u)};
    }
    {
        float4 A0 = *(const float4*)(att + s * 4);
        float4 A1 = *(const float4*)(att + 64 + s * 4);
        at[0] = (f32x2){A0.x, A1.x}; at[1] = (f32x2){A0.y, A1.y};
        at[2] = (f32x2){A0.z, A1.z}; at[3] = (f32x2){A0.w, A1.w};
    }

    f32x2 l2 = (f32x2){0.f, 0.f};
    f32x2 o2[4];
#pragma unroll
    for (int k = 0; k < 4; ++k) o2[k] = (f32x2){0.f, 0.f};

    int e = vn ? head1[nc] : -1;
    uint2 r = rec[e >= 0 ? e : 0];
    int j = (e >= 0) ? (int)r.y : 0;
    uint4 U = *(const uint4*)(xsrc_u + (size_t)j * 64 + s * 4);

    while (__any(e >= 0)) {
        if (e >= 0) {
            int en = (int)r.x;
            uint2 rn = rec[en >= 0 ? en : 0];          // next-hop record prefetch

            unsigned int cu[4] = {U.x, U.y, U.z, U.w};
            f32x2 xj[4];
            f32x2 s2 = (f32x2){0.f, 0.f};
#pragma unroll
            for (int k = 0; k < 4; ++k) {
                xj[k] = (f32x2){__uint_as_float(cu[k] << 16),
                                __uint_as_float(cu[k] & 0xFFFF0000u)};
                f32x2 e2 = xj[k] + xd[k];
                f32x2 e5 = e2 * 0.2f;
                f32x2 le;
                le.x = fmaxf(e2.x, e5.x);
                le.y = fmaxf(e2.y, e5.y);
                s2 += at[k] * le;
            }

            // prefetch next row while reduction + exp + accum run
            int jn = (en >= 0) ? (int)rn.y : 0;
            uint4 Un = *(const uint4*)(xsrc_u + (size_t)jn * 64 + s * 4);

            s2 = row_sum16_2(s2);
            f32x2 w2;
            w2.x = __expf(s2.x);
            w2.y = __expf(s2.y);
            l2 += w2;
#pragma unroll
            for (int k = 0; k < 4; ++k) o2[k] += w2 * xj[k];

            e = en; r = rn; U = Un;
        }
    }

    if (vn) {
        float inv0 = __builtin_amdgcn_rcpf(l2.x + 1e-16f);
        float inv1 = __builtin_amdgcn_rcpf(l2.y + 1e-16f);
        float4 B0 = *(const float4*)(bias + s * 4);
        float4 B1 = *(const float4*)(bias + 64 + s * 4);
        float4 R0 = {o2[0].x * inv0 + B0.x, o2[1].x * inv0 + B0.y,
                     o2[2].x * inv0 + B0.z, o2[3].x * inv0 + B0.w};
        float4 R1 = {o2[0].y * inv1 + B1.x, o2[1].y * inv1 + B1.y,
                     o2[2].y * inv1 + B1.z, o2[3].y * inv1 + B1.w};
        *(float4*)(out + (size_t)node * HC + s * 4) = R0;
        *(float4*)(out + (size_t)node * HC + 64 + s * 4) = R1;
    }
}

extern "C" void kernel_launch(void* const* d_in, const int* in_sizes, int n_in,
                              void* d_out, int out_size, void* d_ws, size_t ws_size,
                              hipStream_t stream) {
    const float* x    = (const float*)d_in[0];
    const int*   ei   = (const int*)d_in[1];
    const float* Ws   = (const float*)d_in[2];
    const float* Wd   = (const float*)d_in[3];
    const float* att  = (const float*)d_in[4];
    const float* bias = (const float*)d_in[5];
    float* out = (float*)d_out;

    const int N = in_sizes[0] / F_IN;
    const int E = in_sizes[1] / 2;
    const int* src = ei;
    const int* dst = ei + E;

    char* ws = (char*)d_ws;
    size_t off = 0;
    auto alloc = [&](size_t bytes) -> char* {
        off = (off + 255) & ~(size_t)255;
        char* p = ws + off;
        off += bytes;
        return p;
    };
    unsigned short* xsrc_pk = (unsigned short*)alloc((size_t)N * HC * sizeof(unsigned short)); // 25.6 MB
    unsigned short* xdst_pk = (unsigned short*)alloc((size_t)N * HC * sizeof(unsigned short)); // 25.6 MB
    unsigned short* PB = (unsigned short*)alloc(256 * 256 * sizeof(unsigned short));           // 128 KB
    int*   head1 = (int*)alloc((size_t)N * sizeof(int));                                       // 400 KB
    uint2* rec   = (uint2*)alloc((size_t)E * sizeof(uint2));                                   // 8 MB

    k_prep<<<32 + 160, 256, 0, stream>>>(Ws, Wd, PB, head1, N);
    k_gemm_list<<<LIST_BLOCKS + (int)((N + 63) / 64), 256, 0, stream>>>(
        x, PB, xsrc_pk, xdst_pk, N, src, dst, E, head1, rec);
    k_agg<<<(N + 15) / 16, 256, 0, stream>>>((const unsigned int*)xsrc_pk,
                                             (const unsigned int*)xdst_pk,
                                             head1, rec, att, bias, out, N);
}